// Round 10
// baseline (241.848 us; speedup 1.0000x reference)
//
#include <hip/hip_runtime.h>

#define LN_EPS 1e-5f

// ---- bf16 helpers (OCP bf16 = top 16 bits of f32, RTNE pack) ----
__device__ __forceinline__ float bflo(unsigned u) { union { unsigned u; float f; } c; c.u = u << 16; return c.f; }
__device__ __forceinline__ float bfhi(unsigned u) { union { unsigned u; float f; } c; c.u = u & 0xffff0000u; return c.f; }
__device__ __forceinline__ unsigned f2bfbits(float f) {
    union { float f; unsigned u; } c; c.f = f;
    return (c.u + 0x7fffu + ((c.u >> 16) & 1u)) >> 16;
}
__device__ __forceinline__ unsigned packbf(float lo, float hi) {
    return f2bfbits(lo) | (f2bfbits(hi) << 16);
}

// ---------------- zero cnt ----------------
__global__ void zero_kernel(int* __restrict__ cnt, int n) {
    int i4 = (blockIdx.x * 256 + threadIdx.x) * 4;
    if (i4 + 3 < n) *(int4*)(cnt + i4) = make_int4(0, 0, 0, 0);
    else for (int k = i4; k < n; ++k) cnt[k] = 0;
}

// ---------------- fused: x->bf16 convert (even blocks) + histogram+rank (odd blocks) + prep ----------------
// Interleaved roles so the BW-bound cvt and latency-bound histogram co-reside on CUs.
__global__ void cvtcnt_kernel(const float* __restrict__ x, unsigned* __restrict__ xb2, int total4,
                              const int* __restrict__ dst, int* __restrict__ cnt,
                              int* __restrict__ rank, int e,
                              const float* __restrict__ W0, const float* __restrict__ Ws,
                              const float* __restrict__ W1,
                              float4* __restrict__ w0i, float4* __restrict__ wsi,
                              float4* __restrict__ w1i, int gM) {
    int b = (int)blockIdx.x;
    if (b < 2 * gM) {
        int idx = b >> 1;
        if ((b & 1) == 0) {
            int i = idx * 256 + threadIdx.x;
            if (i >= total4) return;
            float4 v = ((const float4*)x)[i];
            uint2 o;
            o.x = packbf(v.x, v.y);
            o.y = packbf(v.z, v.w);
            ((uint2*)xb2)[i] = o;
        } else {
            int i = idx * 256 + threadIdx.x;
            if (i >= e) return;
            rank[i] = atomicAdd(&cnt[dst[i]], 1);
        }
    } else {
        int i = (b - 2 * gM) * 256 + threadIdx.x;
        if (i < 1536) {
            int kq = i / 96, j = i % 96;
            const float* p = W0 + kq * 4 * 96 + j;
            w0i[i] = make_float4(p[0], p[96], p[192], p[288]);
            const float* q = Ws + kq * 4 * 96 + j;
            wsi[i] = make_float4(q[0], q[96], q[192], q[288]);
        }
        int i2 = i - 1536;
        if (i2 >= 0 && i2 < 2304) {
            int kq = i2 / 96, j = i2 % 96;
            const float* p = W1 + kq * 4 * 96 + j;
            w1i[i2] = make_float4(p[0], p[96], p[192], p[288]);
        }
    }
}

// ---------------- per-1024-chunk sums of cnt ----------------
__global__ void blocksum_kernel(const int* __restrict__ cnt, int* __restrict__ bsum, int n) {
    int base = blockIdx.x * 1024;
    int t = threadIdx.x;
    int i0 = base + t * 4;
    int s = 0;
    if (i0 + 3 < n) { int4 v = *(const int4*)(cnt + i0); s = v.x + v.y + v.z + v.w; }
    else { for (int k = 0; k < 4; ++k) if (i0 + k < n) s += cnt[i0 + k]; }
    #pragma unroll
    for (int off = 32; off; off >>= 1) s += __shfl_xor(s, off);
    __shared__ int wsum[4];
    if ((t & 63) == 0) wsum[t >> 6] = s;
    __syncthreads();
    if (t == 0) bsum[blockIdx.x] = wsum[0] + wsum[1] + wsum[2] + wsum[3];
}

// ---------------- 1-wave exclusive scan of block sums ----------------
__global__ void scan_bsum_kernel(const int* __restrict__ bsum, int* __restrict__ boff, int nb) {
    int t = threadIdx.x;  // 64
    int carry = 0;
    for (int base = 0; base < nb; base += 64) {
        int i = base + t;
        int v = (i < nb) ? bsum[i] : 0;
        int sc = v;
        #pragma unroll
        for (int off = 1; off < 64; off <<= 1) {
            int u = __shfl_up(sc, off);
            if (t >= off) sc += u;
        }
        if (i < nb) boff[i] = carry + sc - v;
        carry += __shfl(sc, 63);
    }
}

// ---------------- per-chunk rescan -> rowptr ----------------
__global__ void rowptr_kernel(const int* __restrict__ cnt, const int* __restrict__ boff,
                              int* __restrict__ rowptr, int n, int etot) {
    __shared__ int wsum[4];
    int b = blockIdx.x;
    int t = threadIdx.x;
    int i0 = b * 1024 + t * 4;
    int c0 = 0, c1 = 0, c2 = 0, c3 = 0;
    if (i0 < n)     c0 = cnt[i0];
    if (i0 + 1 < n) c1 = cnt[i0 + 1];
    if (i0 + 2 < n) c2 = cnt[i0 + 2];
    if (i0 + 3 < n) c3 = cnt[i0 + 3];
    int tot = c0 + c1 + c2 + c3;
    int lane = t & 63, w = t >> 6;
    int sc = tot;
    #pragma unroll
    for (int off = 1; off < 64; off <<= 1) {
        int u = __shfl_up(sc, off);
        if (lane >= off) sc += u;
    }
    if (lane == 63) wsum[w] = sc;
    __syncthreads();
    int woff = 0;
    for (int k = 0; k < w; ++k) woff += wsum[k];
    int excl = boff[b] + woff + sc - tot;
    if (i0 < n)     rowptr[i0]     = excl;
    if (i0 + 1 < n) rowptr[i0 + 1] = excl + c0;
    if (i0 + 2 < n) rowptr[i0 + 2] = excl + c0 + c1;
    if (i0 + 3 < n) rowptr[i0 + 3] = excl + c0 + c1 + c2;
    if (b == 0 && t == 0) rowptr[n] = etot;
}

// ---------------- XCD-partitioned, atomic-free scatter (1 edge/thread) ----------------
__global__ void scatter_part_kernel(const int* __restrict__ src, const int* __restrict__ dst,
                                    const float* __restrict__ ew, const int* __restrict__ rank,
                                    const int* __restrict__ rowptr,
                                    uint2* __restrict__ cv, int e, int n) {
    int part = blockIdx.x & 7;
    int blk  = blockIdx.x >> 3;
    int chunk = (n + 7) >> 3;
    int lo = part * chunk;
    int hi = lo + chunk; if (hi > n) hi = n;
    int stride = (gridDim.x >> 3) * 256;
    for (int i = blk * 256 + threadIdx.x; i < e; i += stride) {
        int d = dst[i];
        if (d >= lo && d < hi) {
            int pos = rowptr[d] + rank[i];
            cv[pos] = make_uint2((unsigned)src[i], __float_as_uint(ew[i]));
        }
    }
}

// ---------------- deg = 1 + coalesced row sum of raw ew; dinv = rsqrt(deg) ----------------
__global__ void degsum_kernel(const int* __restrict__ rowptr, const uint2* __restrict__ cv,
                              float* __restrict__ dinv, int n) {
    int i = blockIdx.x * 256 + threadIdx.x;
    if (i >= n) return;
    int p0 = rowptr[i], p1 = rowptr[i + 1];
    float s = 1.0f;               // self-loop weight
    for (int p = p0; p < p1; ++p) s += __uint_as_float(cv[p].y);
    dinv[i] = rsqrtf(s);          // deg >= 1 always
}

// ---------------- FUSED agg64 + gemm_ln: 1024 thr, 64 nodes/block ----------------
// phase 1: 16 waves aggregate 4 nodes each, results straight into ar[64][16] (LDS)
//          (the aggX global round-trip is eliminated); xr staged from x.
// phase 2: threads < 512 run the exact register-blocked gemm_ln compute
//          (bit-identical FMA chains) -> hb bf16.
__global__ __launch_bounds__(1024) void agg64_ln_kernel(
        const unsigned* __restrict__ xb, const float* __restrict__ dinv,
        const int* __restrict__ rowptr, const uint2* __restrict__ cv,
        const float4* __restrict__ w0i, const float4* __restrict__ wsi,
        const float* __restrict__ x,
        const float* __restrict__ b0,
        const float* __restrict__ ln_g, const float* __restrict__ ln_b,
        const float* __restrict__ bs,
        unsigned short* __restrict__ hb, int n) {
    __shared__ float4 w0s[1536];   // [16][96]
    __shared__ float4 wss[1536];
    __shared__ float4 ar[1024];    // [64 rows][16]
    __shared__ float4 xr[1024];
    int t = threadIdx.x;
    int base = blockIdx.x * 64;
    for (int i = t; i < 1536; i += 1024) { w0s[i] = w0i[i]; wss[i] = wsi[i]; }
    int rem = n - base; if (rem > 64) rem = 64;
    int nf4 = rem * 16;
    for (int i = t; i < nf4; i += 1024)
        xr[i] = ((const float4*)(x + (size_t)base * 64))[i];

    // ---- phase 1: aggregation (wave w handles nodes base + w*4 .. +3) ----
    int w = t >> 6;
    int lane = t & 63;
    int g = lane >> 4, l4 = lane & 15;
    const uint2* x2 = (const uint2*)xb;   // 8B = 4 bf16; row = 16 x uint2
    #pragma unroll
    for (int rr = 0; rr < 4; ++rr) {
        int nl = w * 4 + rr;              // block-local row
        int node = base + nl;
        if (node < n) {
            int p0 = rowptr[node], pe = rowptr[node + 1];
            float a0 = 0, a1 = 0, a2 = 0, a3 = 0;
            float b0v = 0, b1v = 0, b2v = 0, b3v = 0;
            for (int p = p0 + g; p < pe; p += 8) {
                uint2 e1 = cv[p];
                int s1 = (int)e1.x;
                float w1 = __uint_as_float(e1.y) * dinv[s1];
                uint2 r1 = x2[(size_t)s1 * 16 + l4];
                bool h2 = (p + 4) < pe;
                uint2 e2 = h2 ? cv[p + 4] : e1;
                int s2 = (int)e2.x;
                float w2 = h2 ? __uint_as_float(e2.y) * dinv[s2] : 0.0f;
                uint2 r2 = x2[(size_t)s2 * 16 + l4];
                a0 = fmaf(w1, bflo(r1.x), a0); a1 = fmaf(w1, bfhi(r1.x), a1);
                a2 = fmaf(w1, bflo(r1.y), a2); a3 = fmaf(w1, bfhi(r1.y), a3);
                b0v = fmaf(w2, bflo(r2.x), b0v); b1v = fmaf(w2, bfhi(r2.x), b1v);
                b2v = fmaf(w2, bflo(r2.y), b2v); b3v = fmaf(w2, bfhi(r2.y), b3v);
            }
            a0 += b0v; a1 += b1v; a2 += b2v; a3 += b3v;
            #pragma unroll
            for (int off = 16; off <= 32; off <<= 1) {
                a0 += __shfl_xor(a0, off);
                a1 += __shfl_xor(a1, off);
                a2 += __shfl_xor(a2, off);
                a3 += __shfl_xor(a3, off);
            }
            if (g == 0) {
                float di = dinv[node];
                uint2 sr = x2[(size_t)node * 16 + l4];
                a0 = fmaf(di, bflo(sr.x), a0); a1 = fmaf(di, bfhi(sr.x), a1);
                a2 = fmaf(di, bflo(sr.y), a2); a3 = fmaf(di, bfhi(sr.y), a3);
                ar[nl * 16 + l4] = make_float4(a0 * di, a1 * di, a2 * di, a3 * di);
            }
        }
    }
    __syncthreads();

    // ---- phase 2: register-blocked GEMM + LN (threads < 512, identical to gemm_ln) ----
    if (t >= 512) return;
    int hw = t >> 5;        // 0..15 (32-lane group)
    int l = t & 31;
    int r0 = hw * 4;        // first block-local row of this group
    float acc[4][3] = {{0.f,0.f,0.f},{0.f,0.f,0.f},{0.f,0.f,0.f},{0.f,0.f,0.f}};
    float sk[4][3]  = {{0.f,0.f,0.f},{0.f,0.f,0.f},{0.f,0.f,0.f},{0.f,0.f,0.f}};
    for (int kq = 0; kq < 16; ++kq) {
        float4 wa = w0s[kq * 96 + l];
        float4 wb = w0s[kq * 96 + l + 32];
        float4 wc = w0s[kq * 96 + l + 64];
        float4 sa = wss[kq * 96 + l];
        float4 sb = wss[kq * 96 + l + 32];
        float4 scv = wss[kq * 96 + l + 64];
        #pragma unroll
        for (int r = 0; r < 4; ++r) {
            float4 a  = ar[(r0 + r) * 16 + kq];
            float4 xv = xr[(r0 + r) * 16 + kq];
            acc[r][0] = fmaf(a.w, wa.w, fmaf(a.z, wa.z, fmaf(a.y, wa.y, fmaf(a.x, wa.x, acc[r][0]))));
            acc[r][1] = fmaf(a.w, wb.w, fmaf(a.z, wb.z, fmaf(a.y, wb.y, fmaf(a.x, wb.x, acc[r][1]))));
            acc[r][2] = fmaf(a.w, wc.w, fmaf(a.z, wc.z, fmaf(a.y, wc.y, fmaf(a.x, wc.x, acc[r][2]))));
            sk[r][0]  = fmaf(xv.w, sa.w, fmaf(xv.z, sa.z, fmaf(xv.y, sa.y, fmaf(xv.x, sa.x, sk[r][0]))));
            sk[r][1]  = fmaf(xv.w, sb.w, fmaf(xv.z, sb.z, fmaf(xv.y, sb.y, fmaf(xv.x, sb.x, sk[r][1]))));
            sk[r][2]  = fmaf(xv.w, scv.w, fmaf(xv.z, scv.z, fmaf(xv.y, scv.y, fmaf(xv.x, scv.x, sk[r][2]))));
        }
    }
    float b00 = b0[l], b01 = b0[l + 32], b02 = b0[l + 64];
    float g0 = ln_g[l], g1 = ln_g[l + 32], g2 = ln_g[l + 64];
    float e0 = ln_b[l], e1 = ln_b[l + 32], e2 = ln_b[l + 64];
    float q0 = bs[l],   q1 = bs[l + 32],   q2 = bs[l + 64];
    #pragma unroll
    for (int r = 0; r < 4; ++r) {
        int node = base + r0 + r;
        if (node >= n) break;
        float a0v = acc[r][0] + b00, a1v = acc[r][1] + b01, a2v = acc[r][2] + b02;
        float s1 = a0v + a1v + a2v;
        #pragma unroll
        for (int off = 1; off < 32; off <<= 1) s1 += __shfl_xor(s1, off);
        float mu = s1 * (1.0f / 96.0f);
        float d0 = a0v - mu, d1 = a1v - mu, d2 = a2v - mu;
        float sq = d0 * d0 + d1 * d1 + d2 * d2;
        #pragma unroll
        for (int off = 1; off < 32; off <<= 1) sq += __shfl_xor(sq, off);
        float rinv = rsqrtf(sq * (1.0f / 96.0f) + LN_EPS);
        float v0 = fmaxf(d0 * rinv * g0 + e0, 0.0f) + sk[r][0] + q0;
        float v1 = fmaxf(d1 * rinv * g1 + e1, 0.0f) + sk[r][1] + q1;
        float v2 = fmaxf(d2 * rinv * g2 + e2, 0.0f) + sk[r][2] + q2;
        unsigned short* o = hb + (size_t)node * 96;
        o[l]      = (unsigned short)f2bfbits(v0);
        o[l + 32] = (unsigned short)f2bfbits(v1);
        o[l + 64] = (unsigned short)f2bfbits(v2);
    }
}

// ---------------- FUSED agg96 + gemm_out, cooperative phase-2 ----------------
__global__ __launch_bounds__(1024) void agg96_out_kernel(
        const unsigned short* __restrict__ hb, const float* __restrict__ dinv,
        const int* __restrict__ rowptr, const uint2* __restrict__ cv,
        const float4* __restrict__ w1i, const float* __restrict__ b1,
        float* __restrict__ out, int n) {
    __shared__ float4 w1s[2304];   // [24][96]
    __shared__ float4 hr[384];     // 16 waves x 24 float4 (96 floats each)
    int t = threadIdx.x;
    for (int i = t; i < 2304; i += 1024) w1s[i] = w1i[i];
    int w = t >> 6;
    int node = blockIdx.x * 16 + w;
    int lane = t & 63;
    int g = lane >> 4, l4 = lane & 15;
    if (node < n) {
        const uint4* h4 = (const uint4*)hb;   // 16B = 8 bf16; row = 12 x uint4
        int p0 = rowptr[node], pe = rowptr[node + 1];
        float a0=0,a1=0,a2=0,a3=0,a4=0,a5=0,a6=0,a7=0;
        float c0=0,c1=0,c2=0,c3=0,c4=0,c5=0,c6=0,c7=0;
        if (l4 < 12) {
            for (int p = p0 + g; p < pe; p += 8) {
                uint2 e1 = cv[p];
                int s1 = (int)e1.x;
                float w1 = __uint_as_float(e1.y) * dinv[s1];
                uint4 r1 = h4[(size_t)s1 * 12 + l4];
                bool h2 = (p + 4) < pe;
                uint2 e2 = h2 ? cv[p + 4] : e1;
                int s2 = (int)e2.x;
                float w2 = h2 ? __uint_as_float(e2.y) * dinv[s2] : 0.0f;
                uint4 r2 = h4[(size_t)s2 * 12 + l4];
                a0 = fmaf(w1, bflo(r1.x), a0); a1 = fmaf(w1, bfhi(r1.x), a1);
                a2 = fmaf(w1, bflo(r1.y), a2); a3 = fmaf(w1, bfhi(r1.y), a3);
                a4 = fmaf(w1, bflo(r1.z), a4); a5 = fmaf(w1, bfhi(r1.z), a5);
                a6 = fmaf(w1, bflo(r1.w), a6); a7 = fmaf(w1, bfhi(r1.w), a7);
                c0 = fmaf(w2, bflo(r2.x), c0); c1 = fmaf(w2, bfhi(r2.x), c1);
                c2 = fmaf(w2, bflo(r2.y), c2); c3 = fmaf(w2, bfhi(r2.y), c3);
                c4 = fmaf(w2, bflo(r2.z), c4); c5 = fmaf(w2, bfhi(r2.z), c5);
                c6 = fmaf(w2, bflo(r2.w), c6); c7 = fmaf(w2, bfhi(r2.w), c7);
            }
            a0+=c0; a1+=c1; a2+=c2; a3+=c3; a4+=c4; a5+=c5; a6+=c6; a7+=c7;
        }
        #pragma unroll
        for (int off = 16; off <= 32; off <<= 1) {
            a0 += __shfl_xor(a0, off); a1 += __shfl_xor(a1, off);
            a2 += __shfl_xor(a2, off); a3 += __shfl_xor(a3, off);
            a4 += __shfl_xor(a4, off); a5 += __shfl_xor(a5, off);
            a6 += __shfl_xor(a6, off); a7 += __shfl_xor(a7, off);
        }
        if (g == 0 && l4 < 12) {
            float di = dinv[node];
            uint4 sr = h4[(size_t)node * 12 + l4];
            a0 = fmaf(di, bflo(sr.x), a0); a1 = fmaf(di, bfhi(sr.x), a1);
            a2 = fmaf(di, bflo(sr.y), a2); a3 = fmaf(di, bfhi(sr.y), a3);
            a4 = fmaf(di, bflo(sr.z), a4); a5 = fmaf(di, bfhi(sr.z), a5);
            a6 = fmaf(di, bflo(sr.w), a6); a7 = fmaf(di, bfhi(sr.w), a7);
            hr[w * 24 + l4 * 2]     = make_float4(a0 * di, a1 * di, a2 * di, a3 * di);
            hr[w * 24 + l4 * 2 + 1] = make_float4(a4 * di, a5 * di, a6 * di, a7 * di);
        }
    }
    __syncthreads();
    // phase 2: cooperative GEMM over the 16 staged rows
    int g32 = t >> 5, l = t & 31;
    if (g32 < 24) {
        int rp = g32 / 3;          // 0..7 -> rows rp*2, rp*2+1
        int cb = g32 % 3;          // col block 0..2
        int colbase = cb * 32 + l;
        int r0 = rp * 2;
        float acc0 = 0.f, acc1 = 0.f;
        #pragma unroll 4
        for (int kq = 0; kq < 24; ++kq) {
            float4 wv = w1s[kq * 96 + colbase];
            float4 a0 = hr[r0 * 24 + kq];
            float4 a1 = hr[(r0 + 1) * 24 + kq];
            acc0 = fmaf(a0.w, wv.w, fmaf(a0.z, wv.z, fmaf(a0.y, wv.y, fmaf(a0.x, wv.x, acc0))));
            acc1 = fmaf(a1.w, wv.w, fmaf(a1.z, wv.z, fmaf(a1.y, wv.y, fmaf(a1.x, wv.x, acc1))));
        }
        float bb = b1[colbase];
        int n0 = blockIdx.x * 16 + r0;
        if (n0 < n)     out[(size_t)n0 * 96 + colbase]       = acc0 + bb;
        if (n0 + 1 < n) out[(size_t)(n0 + 1) * 96 + colbase] = acc1 + bb;
    }
}

extern "C" void kernel_launch(void* const* d_in, const int* in_sizes, int n_in,
                              void* d_out, int out_size, void* d_ws, size_t ws_size,
                              hipStream_t stream) {
    const float* x    = (const float*)d_in[0];
    const int*   ei   = (const int*)d_in[1];
    const float* ew   = (const float*)d_in[2];
    const float* W0   = (const float*)d_in[3];
    const float* b0   = (const float*)d_in[4];
    const float* ln_g = (const float*)d_in[5];
    const float* ln_b = (const float*)d_in[6];
    const float* Ws   = (const float*)d_in[7];
    const float* bs   = (const float*)d_in[8];
    const float* W1   = (const float*)d_in[9];
    const float* b1   = (const float*)d_in[10];
    float* out = (float*)d_out;

    const int E = in_sizes[2];          // 800000
    const int N = in_sizes[0] / 64;     // 50000
    const int* src = ei;
    const int* dst = ei + E;

    char* ws = (char*)d_ws;
    size_t off = 0;
    auto alloc = [&](size_t bytes) -> void* {
        void* p = ws + off;
        off = (off + bytes + 255) & ~(size_t)255;
        return p;
    };
    float* dinv   = (float*)alloc((size_t)N * 4);
    int*   cnt    = (int*)alloc((size_t)N * 4);
    int*   rowptr = (int*)alloc((size_t)(N + 1) * 4);
    int*   rank   = (int*)alloc((size_t)E * 4);
    int*   bsum   = (int*)alloc((size_t)256 * 4);
    int*   boff   = (int*)alloc((size_t)256 * 4);
    uint2* cv     = (uint2*)alloc((size_t)E * 8);                // packed (col, raw ew)
    unsigned* xb  = (unsigned*)alloc((size_t)N * 64 * 2);        // bf16 x
    unsigned short* hb = (unsigned short*)alloc((size_t)N * 96 * 2);   // bf16 h, unpadded
    float4* w0i   = (float4*)alloc((size_t)1536 * 16);           // k-interleaved weights
    float4* wsi   = (float4*)alloc((size_t)1536 * 16);
    float4* w1i   = (float4*)alloc((size_t)2304 * 16);

    int gN = (N + 255) / 256;
    int gE = (E + 255) / 256;
    int nb = (N + 1023) / 1024;
    int gX = (N * 16 + 255) / 256;
    int gC = (N / 4 + 255) / 256;
    int gM = gX > gE ? gX : gE;
    int gP = 8 * 128;                   // 8 partitions x 128 blocks

    zero_kernel<<<gC, 256, 0, stream>>>(cnt, N);
    cvtcnt_kernel<<<2 * gM + 15, 256, 0, stream>>>(x, xb, N * 16, dst, cnt, rank, E,
                                                   W0, Ws, W1, w0i, wsi, w1i, gM);
    blocksum_kernel<<<nb, 256, 0, stream>>>(cnt, bsum, N);
    scan_bsum_kernel<<<1, 64, 0, stream>>>(bsum, boff, nb);
    rowptr_kernel<<<nb, 256, 0, stream>>>(cnt, boff, rowptr, N, E);
    scatter_part_kernel<<<gP, 256, 0, stream>>>(src, dst, ew, rank, rowptr, cv, E, N);
    degsum_kernel<<<gN, 256, 0, stream>>>(rowptr, cv, dinv, N);

    int gGL = (N + 63) / 64;
    agg64_ln_kernel<<<gGL, 1024, 0, stream>>>(xb, dinv, rowptr, cv, w0i, wsi, x,
                                              b0, ln_g, ln_b, bs, hb, N);

    int gF = (N + 15) / 16;
    agg96_out_kernel<<<gF, 1024, 0, stream>>>(hb, dinv, rowptr, cv, w1i, b1, out, N);
}

// Round 11
// 211.786 us; speedup vs baseline: 1.1419x; 1.1419x over previous
//
#include <hip/hip_runtime.h>

#define LN_EPS 1e-5f

// ---- bf16 helpers (OCP bf16 = top 16 bits of f32, RTNE pack) ----
__device__ __forceinline__ float bflo(unsigned u) { union { unsigned u; float f; } c; c.u = u << 16; return c.f; }
__device__ __forceinline__ float bfhi(unsigned u) { union { unsigned u; float f; } c; c.u = u & 0xffff0000u; return c.f; }
__device__ __forceinline__ unsigned f2bfbits(float f) {
    union { float f; unsigned u; } c; c.f = f;
    return (c.u + 0x7fffu + ((c.u >> 16) & 1u)) >> 16;
}
__device__ __forceinline__ unsigned packbf(float lo, float hi) {
    return f2bfbits(lo) | (f2bfbits(hi) << 16);
}

// ---------------- zero cnt ----------------
__global__ void zero_kernel(int* __restrict__ cnt, int n) {
    int i4 = (blockIdx.x * 256 + threadIdx.x) * 4;
    if (i4 + 3 < n) *(int4*)(cnt + i4) = make_int4(0, 0, 0, 0);
    else for (int k = i4; k < n; ++k) cnt[k] = 0;
}

// ---------------- fused: x->bf16 convert (even blocks) + histogram+rank (odd blocks) + prep ----------------
// Interleaved roles so the BW-bound cvt and latency-bound histogram co-reside on CUs.
__global__ void cvtcnt_kernel(const float* __restrict__ x, unsigned* __restrict__ xb2, int total4,
                              const int* __restrict__ dst, int* __restrict__ cnt,
                              int* __restrict__ rank, int e,
                              const float* __restrict__ W0, const float* __restrict__ Ws,
                              const float* __restrict__ W1,
                              float4* __restrict__ w0i, float4* __restrict__ wsi,
                              float4* __restrict__ w1i, int gM) {
    int b = (int)blockIdx.x;
    if (b < 2 * gM) {
        int idx = b >> 1;
        if ((b & 1) == 0) {
            int i = idx * 256 + threadIdx.x;
            if (i >= total4) return;
            float4 v = ((const float4*)x)[i];
            uint2 o;
            o.x = packbf(v.x, v.y);
            o.y = packbf(v.z, v.w);
            ((uint2*)xb2)[i] = o;
        } else {
            int i = idx * 256 + threadIdx.x;
            if (i >= e) return;
            rank[i] = atomicAdd(&cnt[dst[i]], 1);
        }
    } else {
        int i = (b - 2 * gM) * 256 + threadIdx.x;
        if (i < 1536) {
            int kq = i / 96, j = i % 96;
            const float* p = W0 + kq * 4 * 96 + j;
            w0i[i] = make_float4(p[0], p[96], p[192], p[288]);
            const float* q = Ws + kq * 4 * 96 + j;
            wsi[i] = make_float4(q[0], q[96], q[192], q[288]);
        }
        int i2 = i - 1536;
        if (i2 >= 0 && i2 < 2304) {
            int kq = i2 / 96, j = i2 % 96;
            const float* p = W1 + kq * 4 * 96 + j;
            w1i[i2] = make_float4(p[0], p[96], p[192], p[288]);
        }
    }
}

// ---------------- per-1024-chunk sums of cnt ----------------
__global__ void blocksum_kernel(const int* __restrict__ cnt, int* __restrict__ bsum, int n) {
    int base = blockIdx.x * 1024;
    int t = threadIdx.x;
    int i0 = base + t * 4;
    int s = 0;
    if (i0 + 3 < n) { int4 v = *(const int4*)(cnt + i0); s = v.x + v.y + v.z + v.w; }
    else { for (int k = 0; k < 4; ++k) if (i0 + k < n) s += cnt[i0 + k]; }
    #pragma unroll
    for (int off = 32; off; off >>= 1) s += __shfl_xor(s, off);
    __shared__ int wsum[4];
    if ((t & 63) == 0) wsum[t >> 6] = s;
    __syncthreads();
    if (t == 0) bsum[blockIdx.x] = wsum[0] + wsum[1] + wsum[2] + wsum[3];
}

// ---------------- 1-wave exclusive scan of block sums ----------------
__global__ void scan_bsum_kernel(const int* __restrict__ bsum, int* __restrict__ boff, int nb) {
    int t = threadIdx.x;  // 64
    int carry = 0;
    for (int base = 0; base < nb; base += 64) {
        int i = base + t;
        int v = (i < nb) ? bsum[i] : 0;
        int sc = v;
        #pragma unroll
        for (int off = 1; off < 64; off <<= 1) {
            int u = __shfl_up(sc, off);
            if (t >= off) sc += u;
        }
        if (i < nb) boff[i] = carry + sc - v;
        carry += __shfl(sc, 63);
    }
}

// ---------------- per-chunk rescan -> rowptr ----------------
__global__ void rowptr_kernel(const int* __restrict__ cnt, const int* __restrict__ boff,
                              int* __restrict__ rowptr, int n, int etot) {
    __shared__ int wsum[4];
    int b = blockIdx.x;
    int t = threadIdx.x;
    int i0 = b * 1024 + t * 4;
    int c0 = 0, c1 = 0, c2 = 0, c3 = 0;
    if (i0 < n)     c0 = cnt[i0];
    if (i0 + 1 < n) c1 = cnt[i0 + 1];
    if (i0 + 2 < n) c2 = cnt[i0 + 2];
    if (i0 + 3 < n) c3 = cnt[i0 + 3];
    int tot = c0 + c1 + c2 + c3;
    int lane = t & 63, w = t >> 6;
    int sc = tot;
    #pragma unroll
    for (int off = 1; off < 64; off <<= 1) {
        int u = __shfl_up(sc, off);
        if (lane >= off) sc += u;
    }
    if (lane == 63) wsum[w] = sc;
    __syncthreads();
    int woff = 0;
    for (int k = 0; k < w; ++k) woff += wsum[k];
    int excl = boff[b] + woff + sc - tot;
    if (i0 < n)     rowptr[i0]     = excl;
    if (i0 + 1 < n) rowptr[i0 + 1] = excl + c0;
    if (i0 + 2 < n) rowptr[i0 + 2] = excl + c0 + c1;
    if (i0 + 3 < n) rowptr[i0 + 3] = excl + c0 + c1 + c2;
    if (b == 0 && t == 0) rowptr[n] = etot;
}

// ---------------- XCD-partitioned, atomic-free scatter (1 edge/thread) ----------------
__global__ void scatter_part_kernel(const int* __restrict__ src, const int* __restrict__ dst,
                                    const float* __restrict__ ew, const int* __restrict__ rank,
                                    const int* __restrict__ rowptr,
                                    uint2* __restrict__ cv, int e, int n) {
    int part = blockIdx.x & 7;
    int blk  = blockIdx.x >> 3;
    int chunk = (n + 7) >> 3;
    int lo = part * chunk;
    int hi = lo + chunk; if (hi > n) hi = n;
    int stride = (gridDim.x >> 3) * 256;
    for (int i = blk * 256 + threadIdx.x; i < e; i += stride) {
        int d = dst[i];
        if (d >= lo && d < hi) {
            int pos = rowptr[d] + rank[i];
            cv[pos] = make_uint2((unsigned)src[i], __float_as_uint(ew[i]));
        }
    }
}

// ---------------- deg = 1 + coalesced row sum of raw ew; dinv = rsqrt(deg) ----------------
__global__ void degsum_kernel(const int* __restrict__ rowptr, const uint2* __restrict__ cv,
                              float* __restrict__ dinv, int n) {
    int i = blockIdx.x * 256 + threadIdx.x;
    if (i >= n) return;
    int p0 = rowptr[i], p1 = rowptr[i + 1];
    float s = 1.0f;               // self-loop weight
    for (int p = p0; p < p1; ++p) s += __uint_as_float(cv[p].y);
    dinv[i] = rsqrtf(s);          // deg >= 1 always
}

// ---------------- agg of xb (64 bf16): wave/node, 4 groups x 16 lanes x 8B ----------------
// out[d] = di * ( sum_p ew[p]*dinv[col[p]]*x[col[p]] + di * x[d] )
__global__ void agg64_kernel(const unsigned* __restrict__ xb, const float* __restrict__ dinv,
                             const int* __restrict__ rowptr, const uint2* __restrict__ cv,
                             float* __restrict__ aggX, int n) {
    int node = blockIdx.x * 4 + (threadIdx.x >> 6);
    if (node >= n) return;
    int lane = threadIdx.x & 63;
    int g = lane >> 4, l4 = lane & 15;
    const uint2* x2 = (const uint2*)xb;   // 8B = 4 bf16; row = 16 x uint2
    int p0 = rowptr[node], pe = rowptr[node + 1];
    float a0 = 0, a1 = 0, a2 = 0, a3 = 0;
    float b0 = 0, b1 = 0, b2 = 0, b3 = 0;
    for (int p = p0 + g; p < pe; p += 8) {
        uint2 e1 = cv[p];
        int s1 = (int)e1.x;
        float w1 = __uint_as_float(e1.y) * dinv[s1];
        uint2 r1 = x2[(size_t)s1 * 16 + l4];
        bool h2 = (p + 4) < pe;
        uint2 e2 = h2 ? cv[p + 4] : e1;
        int s2 = (int)e2.x;
        float w2 = h2 ? __uint_as_float(e2.y) * dinv[s2] : 0.0f;
        uint2 r2 = x2[(size_t)s2 * 16 + l4];
        a0 = fmaf(w1, bflo(r1.x), a0); a1 = fmaf(w1, bfhi(r1.x), a1);
        a2 = fmaf(w1, bflo(r1.y), a2); a3 = fmaf(w1, bfhi(r1.y), a3);
        b0 = fmaf(w2, bflo(r2.x), b0); b1 = fmaf(w2, bfhi(r2.x), b1);
        b2 = fmaf(w2, bflo(r2.y), b2); b3 = fmaf(w2, bfhi(r2.y), b3);
    }
    a0 += b0; a1 += b1; a2 += b2; a3 += b3;
    #pragma unroll
    for (int off = 16; off <= 32; off <<= 1) {
        a0 += __shfl_xor(a0, off);
        a1 += __shfl_xor(a1, off);
        a2 += __shfl_xor(a2, off);
        a3 += __shfl_xor(a3, off);
    }
    if (g == 0) {
        float di = dinv[node];
        uint2 sr = x2[(size_t)node * 16 + l4];
        a0 = fmaf(di, bflo(sr.x), a0); a1 = fmaf(di, bfhi(sr.x), a1);
        a2 = fmaf(di, bflo(sr.y), a2); a3 = fmaf(di, bfhi(sr.y), a3);
        ((float4*)(aggX + (size_t)node * 64))[l4] =
            make_float4(a0 * di, a1 * di, a2 * di, a3 * di);
    }
}

// ---------------- fused layer0: h = relu(LN(aggX@W0+b0)) + x@Ws + bs -> bf16 (96, unpadded) ----------------
__global__ __launch_bounds__(512) void gemm_ln_kernel(
        const float4* __restrict__ w0i, const float4* __restrict__ wsi,
        const float* __restrict__ aggX, const float* __restrict__ x,
        const float* __restrict__ b0,
        const float* __restrict__ ln_g, const float* __restrict__ ln_b,
        const float* __restrict__ bs,
        unsigned short* __restrict__ hb, int n) {
    __shared__ float4 w0s[1536];   // [16][96]
    __shared__ float4 wss[1536];
    __shared__ float4 ar[1024];    // [64 rows][16]
    __shared__ float4 xr[1024];
    int t = threadIdx.x;
    int base = blockIdx.x * 64;
    for (int i = t; i < 1536; i += 512) { w0s[i] = w0i[i]; wss[i] = wsi[i]; }
    int rem = n - base; if (rem > 64) rem = 64;
    int nf4 = rem * 16;
    for (int i = t; i < nf4; i += 512) {
        ar[i] = ((const float4*)(aggX + (size_t)base * 64))[i];
        xr[i] = ((const float4*)(x + (size_t)base * 64))[i];
    }
    __syncthreads();
    int hw = t >> 5;        // 0..15 (32-lane group)
    int l = t & 31;
    int r0 = hw * 4;        // first block-local row of this group
    float acc[4][3] = {{0.f,0.f,0.f},{0.f,0.f,0.f},{0.f,0.f,0.f},{0.f,0.f,0.f}};
    float sk[4][3]  = {{0.f,0.f,0.f},{0.f,0.f,0.f},{0.f,0.f,0.f},{0.f,0.f,0.f}};
    for (int kq = 0; kq < 16; ++kq) {
        float4 wa = w0s[kq * 96 + l];
        float4 wb = w0s[kq * 96 + l + 32];
        float4 wc = w0s[kq * 96 + l + 64];
        float4 sa = wss[kq * 96 + l];
        float4 sb = wss[kq * 96 + l + 32];
        float4 scv = wss[kq * 96 + l + 64];
        #pragma unroll
        for (int r = 0; r < 4; ++r) {
            float4 a  = ar[(r0 + r) * 16 + kq];
            float4 xv = xr[(r0 + r) * 16 + kq];
            acc[r][0] = fmaf(a.w, wa.w, fmaf(a.z, wa.z, fmaf(a.y, wa.y, fmaf(a.x, wa.x, acc[r][0]))));
            acc[r][1] = fmaf(a.w, wb.w, fmaf(a.z, wb.z, fmaf(a.y, wb.y, fmaf(a.x, wb.x, acc[r][1]))));
            acc[r][2] = fmaf(a.w, wc.w, fmaf(a.z, wc.z, fmaf(a.y, wc.y, fmaf(a.x, wc.x, acc[r][2]))));
            sk[r][0]  = fmaf(xv.w, sa.w, fmaf(xv.z, sa.z, fmaf(xv.y, sa.y, fmaf(xv.x, sa.x, sk[r][0]))));
            sk[r][1]  = fmaf(xv.w, sb.w, fmaf(xv.z, sb.z, fmaf(xv.y, sb.y, fmaf(xv.x, sb.x, sk[r][1]))));
            sk[r][2]  = fmaf(xv.w, scv.w, fmaf(xv.z, scv.z, fmaf(xv.y, scv.y, fmaf(xv.x, scv.x, sk[r][2]))));
        }
    }
    float b00 = b0[l], b01 = b0[l + 32], b02 = b0[l + 64];
    float g0 = ln_g[l], g1 = ln_g[l + 32], g2 = ln_g[l + 64];
    float e0 = ln_b[l], e1 = ln_b[l + 32], e2 = ln_b[l + 64];
    float q0 = bs[l],   q1 = bs[l + 32],   q2 = bs[l + 64];
    #pragma unroll
    for (int r = 0; r < 4; ++r) {
        int node = base + r0 + r;
        if (node >= n) break;
        float a0v = acc[r][0] + b00, a1v = acc[r][1] + b01, a2v = acc[r][2] + b02;
        float s1 = a0v + a1v + a2v;
        #pragma unroll
        for (int off = 1; off < 32; off <<= 1) s1 += __shfl_xor(s1, off);
        float mu = s1 * (1.0f / 96.0f);
        float d0 = a0v - mu, d1 = a1v - mu, d2 = a2v - mu;
        float sq = d0 * d0 + d1 * d1 + d2 * d2;
        #pragma unroll
        for (int off = 1; off < 32; off <<= 1) sq += __shfl_xor(sq, off);
        float rinv = rsqrtf(sq * (1.0f / 96.0f) + LN_EPS);
        float v0 = fmaxf(d0 * rinv * g0 + e0, 0.0f) + sk[r][0] + q0;
        float v1 = fmaxf(d1 * rinv * g1 + e1, 0.0f) + sk[r][1] + q1;
        float v2 = fmaxf(d2 * rinv * g2 + e2, 0.0f) + sk[r][2] + q2;
        unsigned short* o = hb + (size_t)node * 96;
        o[l]      = (unsigned short)f2bfbits(v0);
        o[l + 32] = (unsigned short)f2bfbits(v1);
        o[l + 64] = (unsigned short)f2bfbits(v2);
    }
}

// ---------------- FUSED agg96 + gemm_out, cooperative phase-2 ----------------
__global__ __launch_bounds__(1024) void agg96_out_kernel(
        const unsigned short* __restrict__ hb, const float* __restrict__ dinv,
        const int* __restrict__ rowptr, const uint2* __restrict__ cv,
        const float4* __restrict__ w1i, const float* __restrict__ b1,
        float* __restrict__ out, int n) {
    __shared__ float4 w1s[2304];   // [24][96]
    __shared__ float4 hr[384];     // 16 waves x 24 float4 (96 floats each)
    int t = threadIdx.x;
    for (int i = t; i < 2304; i += 1024) w1s[i] = w1i[i];
    int w = t >> 6;
    int node = blockIdx.x * 16 + w;
    int lane = t & 63;
    int g = lane >> 4, l4 = lane & 15;
    if (node < n) {
        const uint4* h4 = (const uint4*)hb;   // 16B = 8 bf16; row = 12 x uint4
        int p0 = rowptr[node], pe = rowptr[node + 1];
        float a0=0,a1=0,a2=0,a3=0,a4=0,a5=0,a6=0,a7=0;
        float c0=0,c1=0,c2=0,c3=0,c4=0,c5=0,c6=0,c7=0;
        if (l4 < 12) {
            for (int p = p0 + g; p < pe; p += 8) {
                uint2 e1 = cv[p];
                int s1 = (int)e1.x;
                float w1 = __uint_as_float(e1.y) * dinv[s1];
                uint4 r1 = h4[(size_t)s1 * 12 + l4];
                bool h2 = (p + 4) < pe;
                uint2 e2 = h2 ? cv[p + 4] : e1;
                int s2 = (int)e2.x;
                float w2 = h2 ? __uint_as_float(e2.y) * dinv[s2] : 0.0f;
                uint4 r2 = h4[(size_t)s2 * 12 + l4];
                a0 = fmaf(w1, bflo(r1.x), a0); a1 = fmaf(w1, bfhi(r1.x), a1);
                a2 = fmaf(w1, bflo(r1.y), a2); a3 = fmaf(w1, bfhi(r1.y), a3);
                a4 = fmaf(w1, bflo(r1.z), a4); a5 = fmaf(w1, bfhi(r1.z), a5);
                a6 = fmaf(w1, bflo(r1.w), a6); a7 = fmaf(w1, bfhi(r1.w), a7);
                c0 = fmaf(w2, bflo(r2.x), c0); c1 = fmaf(w2, bfhi(r2.x), c1);
                c2 = fmaf(w2, bflo(r2.y), c2); c3 = fmaf(w2, bfhi(r2.y), c3);
                c4 = fmaf(w2, bflo(r2.z), c4); c5 = fmaf(w2, bfhi(r2.z), c5);
                c6 = fmaf(w2, bflo(r2.w), c6); c7 = fmaf(w2, bfhi(r2.w), c7);
            }
            a0+=c0; a1+=c1; a2+=c2; a3+=c3; a4+=c4; a5+=c5; a6+=c6; a7+=c7;
        }
        #pragma unroll
        for (int off = 16; off <= 32; off <<= 1) {
            a0 += __shfl_xor(a0, off); a1 += __shfl_xor(a1, off);
            a2 += __shfl_xor(a2, off); a3 += __shfl_xor(a3, off);
            a4 += __shfl_xor(a4, off); a5 += __shfl_xor(a5, off);
            a6 += __shfl_xor(a6, off); a7 += __shfl_xor(a7, off);
        }
        if (g == 0 && l4 < 12) {
            float di = dinv[node];
            uint4 sr = h4[(size_t)node * 12 + l4];
            a0 = fmaf(di, bflo(sr.x), a0); a1 = fmaf(di, bfhi(sr.x), a1);
            a2 = fmaf(di, bflo(sr.y), a2); a3 = fmaf(di, bfhi(sr.y), a3);
            a4 = fmaf(di, bflo(sr.z), a4); a5 = fmaf(di, bfhi(sr.z), a5);
            a6 = fmaf(di, bflo(sr.w), a6); a7 = fmaf(di, bfhi(sr.w), a7);
            hr[w * 24 + l4 * 2]     = make_float4(a0 * di, a1 * di, a2 * di, a3 * di);
            hr[w * 24 + l4 * 2 + 1] = make_float4(a4 * di, a5 * di, a6 * di, a7 * di);
        }
    }
    __syncthreads();
    // phase 2: cooperative GEMM over the 16 staged rows
    int g32 = t >> 5, l = t & 31;
    if (g32 < 24) {
        int rp = g32 / 3;          // 0..7 -> rows rp*2, rp*2+1
        int cb = g32 % 3;          // col block 0..2
        int colbase = cb * 32 + l;
        int r0 = rp * 2;
        float acc0 = 0.f, acc1 = 0.f;
        #pragma unroll 4
        for (int kq = 0; kq < 24; ++kq) {
            float4 wv = w1s[kq * 96 + colbase];
            float4 a0 = hr[r0 * 24 + kq];
            float4 a1 = hr[(r0 + 1) * 24 + kq];
            acc0 = fmaf(a0.w, wv.w, fmaf(a0.z, wv.z, fmaf(a0.y, wv.y, fmaf(a0.x, wv.x, acc0))));
            acc1 = fmaf(a1.w, wv.w, fmaf(a1.z, wv.z, fmaf(a1.y, wv.y, fmaf(a1.x, wv.x, acc1))));
        }
        float bb = b1[colbase];
        int n0 = blockIdx.x * 16 + r0;
        if (n0 < n)     out[(size_t)n0 * 96 + colbase]       = acc0 + bb;
        if (n0 + 1 < n) out[(size_t)(n0 + 1) * 96 + colbase] = acc1 + bb;
    }
}

extern "C" void kernel_launch(void* const* d_in, const int* in_sizes, int n_in,
                              void* d_out, int out_size, void* d_ws, size_t ws_size,
                              hipStream_t stream) {
    const float* x    = (const float*)d_in[0];
    const int*   ei   = (const int*)d_in[1];
    const float* ew   = (const float*)d_in[2];
    const float* W0   = (const float*)d_in[3];
    const float* b0   = (const float*)d_in[4];
    const float* ln_g = (const float*)d_in[5];
    const float* ln_b = (const float*)d_in[6];
    const float* Ws   = (const float*)d_in[7];
    const float* bs   = (const float*)d_in[8];
    const float* W1   = (const float*)d_in[9];
    const float* b1   = (const float*)d_in[10];
    float* out = (float*)d_out;

    const int E = in_sizes[2];          // 800000
    const int N = in_sizes[0] / 64;     // 50000
    const int* src = ei;
    const int* dst = ei + E;

    char* ws = (char*)d_ws;
    size_t off = 0;
    auto alloc = [&](size_t bytes) -> void* {
        void* p = ws + off;
        off = (off + bytes + 255) & ~(size_t)255;
        return p;
    };
    float* dinv   = (float*)alloc((size_t)N * 4);
    int*   cnt    = (int*)alloc((size_t)N * 4);
    int*   rowptr = (int*)alloc((size_t)(N + 1) * 4);
    int*   rank   = (int*)alloc((size_t)E * 4);
    int*   bsum   = (int*)alloc((size_t)256 * 4);
    int*   boff   = (int*)alloc((size_t)256 * 4);
    uint2* cv     = (uint2*)alloc((size_t)E * 8);                // packed (col, raw ew)
    unsigned* xb  = (unsigned*)alloc((size_t)N * 64 * 2);        // bf16 x
    unsigned short* hb = (unsigned short*)alloc((size_t)N * 96 * 2);   // bf16 h, unpadded
    float* bufA   = (float*)alloc((size_t)N * 64 * 4);           // aggX
    float4* w0i   = (float4*)alloc((size_t)1536 * 16);           // k-interleaved weights
    float4* wsi   = (float4*)alloc((size_t)1536 * 16);
    float4* w1i   = (float4*)alloc((size_t)2304 * 16);

    int gN = (N + 255) / 256;
    int gE = (E + 255) / 256;
    int nb = (N + 1023) / 1024;
    int gX = (N * 16 + 255) / 256;
    int gC = (N / 4 + 255) / 256;
    int gM = gX > gE ? gX : gE;
    int gP = 8 * 128;                   // 8 partitions x 128 blocks

    zero_kernel<<<gC, 256, 0, stream>>>(cnt, N);
    cvtcnt_kernel<<<2 * gM + 15, 256, 0, stream>>>(x, xb, N * 16, dst, cnt, rank, E,
                                                   W0, Ws, W1, w0i, wsi, w1i, gM);
    blocksum_kernel<<<nb, 256, 0, stream>>>(cnt, bsum, N);
    scan_bsum_kernel<<<1, 64, 0, stream>>>(bsum, boff, nb);
    rowptr_kernel<<<nb, 256, 0, stream>>>(cnt, boff, rowptr, N, E);
    scatter_part_kernel<<<gP, 256, 0, stream>>>(src, dst, ew, rank, rowptr, cv, E, N);
    degsum_kernel<<<gN, 256, 0, stream>>>(rowptr, cv, dinv, N);

    int gA = (N + 3) / 4;
    agg64_kernel<<<gA, 256, 0, stream>>>(xb, dinv, rowptr, cv, bufA, N);

    int gG = (N + 63) / 64;
    gemm_ln_kernel<<<gG, 512, 0, stream>>>(w0i, wsi, bufA, x, b0, ln_g, ln_b, bs, hb, N);

    int gF = (N + 15) / 16;
    agg96_out_kernel<<<gF, 1024, 0, stream>>>(hb, dinv, rowptr, cv, w1i, b1, out, N);
}

// Round 12
// 201.306 us; speedup vs baseline: 1.2014x; 1.0521x over previous
//
#include <hip/hip_runtime.h>

#define LN_EPS 1e-5f

// ---- bf16 helpers (OCP bf16 = top 16 bits of f32, RTNE pack) ----
__device__ __forceinline__ float bflo(unsigned u) { union { unsigned u; float f; } c; c.u = u << 16; return c.f; }
__device__ __forceinline__ float bfhi(unsigned u) { union { unsigned u; float f; } c; c.u = u & 0xffff0000u; return c.f; }
__device__ __forceinline__ unsigned f2bfbits(float f) {
    union { float f; unsigned u; } c; c.f = f;
    return (c.u + 0x7fffu + ((c.u >> 16) & 1u)) >> 16;
}
__device__ __forceinline__ unsigned packbf(float lo, float hi) {
    return f2bfbits(lo) | (f2bfbits(hi) << 16);
}

// ---------------- zero cnt ----------------
__global__ void zero_kernel(int* __restrict__ cnt, int n) {
    int i4 = (blockIdx.x * 256 + threadIdx.x) * 4;
    if (i4 + 3 < n) *(int4*)(cnt + i4) = make_int4(0, 0, 0, 0);
    else for (int k = i4; k < n; ++k) cnt[k] = 0;
}

// ---------------- fused: x->bf16 convert (even blocks) + histogram+rank (odd blocks) + prep ----------------
__global__ void cvtcnt_kernel(const float* __restrict__ x, unsigned* __restrict__ xb2, int total4,
                              const int* __restrict__ dst, int* __restrict__ cnt,
                              int* __restrict__ rank, int e,
                              const float* __restrict__ W0, const float* __restrict__ Ws,
                              const float* __restrict__ W1,
                              float4* __restrict__ w0i, float4* __restrict__ wsi,
                              float4* __restrict__ w1i, int gM) {
    int b = (int)blockIdx.x;
    if (b < 2 * gM) {
        int idx = b >> 1;
        if ((b & 1) == 0) {
            int i = idx * 256 + threadIdx.x;
            if (i >= total4) return;
            float4 v = ((const float4*)x)[i];
            uint2 o;
            o.x = packbf(v.x, v.y);
            o.y = packbf(v.z, v.w);
            ((uint2*)xb2)[i] = o;
        } else {
            int i = idx * 256 + threadIdx.x;
            if (i >= e) return;
            rank[i] = atomicAdd(&cnt[dst[i]], 1);
        }
    } else {
        int i = (b - 2 * gM) * 256 + threadIdx.x;
        if (i < 1536) {
            int kq = i / 96, j = i % 96;
            const float* p = W0 + kq * 4 * 96 + j;
            w0i[i] = make_float4(p[0], p[96], p[192], p[288]);
            const float* q = Ws + kq * 4 * 96 + j;
            wsi[i] = make_float4(q[0], q[96], q[192], q[288]);
        }
        int i2 = i - 1536;
        if (i2 >= 0 && i2 < 2304) {
            int kq = i2 / 96, j = i2 % 96;
            const float* p = W1 + kq * 4 * 96 + j;
            w1i[i2] = make_float4(p[0], p[96], p[192], p[288]);
        }
    }
}

// ---------------- per-1024-chunk sums of cnt ----------------
__global__ void blocksum_kernel(const int* __restrict__ cnt, int* __restrict__ bsum, int n) {
    int base = blockIdx.x * 1024;
    int t = threadIdx.x;
    int i0 = base + t * 4;
    int s = 0;
    if (i0 + 3 < n) { int4 v = *(const int4*)(cnt + i0); s = v.x + v.y + v.z + v.w; }
    else { for (int k = 0; k < 4; ++k) if (i0 + k < n) s += cnt[i0 + k]; }
    #pragma unroll
    for (int off = 32; off; off >>= 1) s += __shfl_xor(s, off);
    __shared__ int wsum[4];
    if ((t & 63) == 0) wsum[t >> 6] = s;
    __syncthreads();
    if (t == 0) bsum[blockIdx.x] = wsum[0] + wsum[1] + wsum[2] + wsum[3];
}

// ---------------- 1-wave exclusive scan of block sums ----------------
__global__ void scan_bsum_kernel(const int* __restrict__ bsum, int* __restrict__ boff, int nb) {
    int t = threadIdx.x;  // 64
    int carry = 0;
    for (int base = 0; base < nb; base += 64) {
        int i = base + t;
        int v = (i < nb) ? bsum[i] : 0;
        int sc = v;
        #pragma unroll
        for (int off = 1; off < 64; off <<= 1) {
            int u = __shfl_up(sc, off);
            if (t >= off) sc += u;
        }
        if (i < nb) boff[i] = carry + sc - v;
        carry += __shfl(sc, 63);
    }
}

// ---------------- per-chunk rescan -> rowptr ----------------
__global__ void rowptr_kernel(const int* __restrict__ cnt, const int* __restrict__ boff,
                              int* __restrict__ rowptr, int n, int etot) {
    __shared__ int wsum[4];
    int b = blockIdx.x;
    int t = threadIdx.x;
    int i0 = b * 1024 + t * 4;
    int c0 = 0, c1 = 0, c2 = 0, c3 = 0;
    if (i0 < n)     c0 = cnt[i0];
    if (i0 + 1 < n) c1 = cnt[i0 + 1];
    if (i0 + 2 < n) c2 = cnt[i0 + 2];
    if (i0 + 3 < n) c3 = cnt[i0 + 3];
    int tot = c0 + c1 + c2 + c3;
    int lane = t & 63, w = t >> 6;
    int sc = tot;
    #pragma unroll
    for (int off = 1; off < 64; off <<= 1) {
        int u = __shfl_up(sc, off);
        if (lane >= off) sc += u;
    }
    if (lane == 63) wsum[w] = sc;
    __syncthreads();
    int woff = 0;
    for (int k = 0; k < w; ++k) woff += wsum[k];
    int excl = boff[b] + woff + sc - tot;
    if (i0 < n)     rowptr[i0]     = excl;
    if (i0 + 1 < n) rowptr[i0 + 1] = excl + c0;
    if (i0 + 2 < n) rowptr[i0 + 2] = excl + c0 + c1;
    if (i0 + 3 < n) rowptr[i0 + 3] = excl + c0 + c1 + c2;
    if (b == 0 && t == 0) rowptr[n] = etot;
}

// ---------------- XCD-partitioned, atomic-free scatter (1 edge/thread) ----------------
__global__ void scatter_part_kernel(const int* __restrict__ src, const int* __restrict__ dst,
                                    const float* __restrict__ ew, const int* __restrict__ rank,
                                    const int* __restrict__ rowptr,
                                    uint2* __restrict__ cv, int e, int n) {
    int part = blockIdx.x & 7;
    int blk  = blockIdx.x >> 3;
    int chunk = (n + 7) >> 3;
    int lo = part * chunk;
    int hi = lo + chunk; if (hi > n) hi = n;
    int stride = (gridDim.x >> 3) * 256;
    for (int i = blk * 256 + threadIdx.x; i < e; i += stride) {
        int d = dst[i];
        if (d >= lo && d < hi) {
            int pos = rowptr[d] + rank[i];
            cv[pos] = make_uint2((unsigned)src[i], __float_as_uint(ew[i]));
        }
    }
}

// ---------------- deg = 1 + coalesced row sum of raw ew; dinv = rsqrt(deg) ----------------
__global__ void degsum_kernel(const int* __restrict__ rowptr, const uint2* __restrict__ cv,
                              float* __restrict__ dinv, int n) {
    int i = blockIdx.x * 256 + threadIdx.x;
    if (i >= n) return;
    int p0 = rowptr[i], p1 = rowptr[i + 1];
    float s = 1.0f;               // self-loop weight
    for (int p = p0; p < p1; ++p) s += __uint_as_float(cv[p].y);
    dinv[i] = rsqrtf(s);          // deg >= 1 always
}

// ---------------- agg of xb (64 bf16): wave/node, 4 groups x 16 lanes x 8B ----------------
// out[d] = di * ( sum_p ew[p]*dinv[col[p]]*x[col[p]] + di * x[d] )
__global__ void agg64_kernel(const unsigned* __restrict__ xb, const float* __restrict__ dinv,
                             const int* __restrict__ rowptr, const uint2* __restrict__ cv,
                             float* __restrict__ aggX, int n) {
    int node = blockIdx.x * 4 + (threadIdx.x >> 6);
    if (node >= n) return;
    int lane = threadIdx.x & 63;
    int g = lane >> 4, l4 = lane & 15;
    const uint2* x2 = (const uint2*)xb;   // 8B = 4 bf16; row = 16 x uint2
    int p0 = rowptr[node], pe = rowptr[node + 1];
    float a0 = 0, a1 = 0, a2 = 0, a3 = 0;
    float b0 = 0, b1 = 0, b2 = 0, b3 = 0;
    for (int p = p0 + g; p < pe; p += 8) {
        uint2 e1 = cv[p];
        int s1 = (int)e1.x;
        float w1 = __uint_as_float(e1.y) * dinv[s1];
        uint2 r1 = x2[(size_t)s1 * 16 + l4];
        bool h2 = (p + 4) < pe;
        uint2 e2 = h2 ? cv[p + 4] : e1;
        int s2 = (int)e2.x;
        float w2 = h2 ? __uint_as_float(e2.y) * dinv[s2] : 0.0f;
        uint2 r2 = x2[(size_t)s2 * 16 + l4];
        a0 = fmaf(w1, bflo(r1.x), a0); a1 = fmaf(w1, bfhi(r1.x), a1);
        a2 = fmaf(w1, bflo(r1.y), a2); a3 = fmaf(w1, bfhi(r1.y), a3);
        b0 = fmaf(w2, bflo(r2.x), b0); b1 = fmaf(w2, bfhi(r2.x), b1);
        b2 = fmaf(w2, bflo(r2.y), b2); b3 = fmaf(w2, bfhi(r2.y), b3);
    }
    a0 += b0; a1 += b1; a2 += b2; a3 += b3;
    #pragma unroll
    for (int off = 16; off <= 32; off <<= 1) {
        a0 += __shfl_xor(a0, off);
        a1 += __shfl_xor(a1, off);
        a2 += __shfl_xor(a2, off);
        a3 += __shfl_xor(a3, off);
    }
    if (g == 0) {
        float di = dinv[node];
        uint2 sr = x2[(size_t)node * 16 + l4];
        a0 = fmaf(di, bflo(sr.x), a0); a1 = fmaf(di, bfhi(sr.x), a1);
        a2 = fmaf(di, bflo(sr.y), a2); a3 = fmaf(di, bfhi(sr.y), a3);
        ((float4*)(aggX + (size_t)node * 64))[l4] =
            make_float4(a0 * di, a1 * di, a2 * di, a3 * di);
    }
}

// ---------------- fused layer0 -> hb stores hs = (relu(LN(aggX@W0+b0)) + x@Ws+bs) * dinv[node] ----------------
__global__ __launch_bounds__(512) void gemm_ln_kernel(
        const float4* __restrict__ w0i, const float4* __restrict__ wsi,
        const float* __restrict__ aggX, const float* __restrict__ x,
        const float* __restrict__ dinv,
        const float* __restrict__ b0,
        const float* __restrict__ ln_g, const float* __restrict__ ln_b,
        const float* __restrict__ bs,
        unsigned short* __restrict__ hb, int n) {
    __shared__ float4 w0s[1536];   // [16][96]
    __shared__ float4 wss[1536];
    __shared__ float4 ar[1024];    // [64 rows][16]
    __shared__ float4 xr[1024];
    int t = threadIdx.x;
    int base = blockIdx.x * 64;
    for (int i = t; i < 1536; i += 512) { w0s[i] = w0i[i]; wss[i] = wsi[i]; }
    int rem = n - base; if (rem > 64) rem = 64;
    int nf4 = rem * 16;
    for (int i = t; i < nf4; i += 512) {
        ar[i] = ((const float4*)(aggX + (size_t)base * 64))[i];
        xr[i] = ((const float4*)(x + (size_t)base * 64))[i];
    }
    __syncthreads();
    int hw = t >> 5;        // 0..15 (32-lane group)
    int l = t & 31;
    int r0 = hw * 4;        // first block-local row of this group
    float acc[4][3] = {{0.f,0.f,0.f},{0.f,0.f,0.f},{0.f,0.f,0.f},{0.f,0.f,0.f}};
    float sk[4][3]  = {{0.f,0.f,0.f},{0.f,0.f,0.f},{0.f,0.f,0.f},{0.f,0.f,0.f}};
    for (int kq = 0; kq < 16; ++kq) {
        float4 wa = w0s[kq * 96 + l];
        float4 wb = w0s[kq * 96 + l + 32];
        float4 wc = w0s[kq * 96 + l + 64];
        float4 sa = wss[kq * 96 + l];
        float4 sb = wss[kq * 96 + l + 32];
        float4 scv = wss[kq * 96 + l + 64];
        #pragma unroll
        for (int r = 0; r < 4; ++r) {
            float4 a  = ar[(r0 + r) * 16 + kq];
            float4 xv = xr[(r0 + r) * 16 + kq];
            acc[r][0] = fmaf(a.w, wa.w, fmaf(a.z, wa.z, fmaf(a.y, wa.y, fmaf(a.x, wa.x, acc[r][0]))));
            acc[r][1] = fmaf(a.w, wb.w, fmaf(a.z, wb.z, fmaf(a.y, wb.y, fmaf(a.x, wb.x, acc[r][1]))));
            acc[r][2] = fmaf(a.w, wc.w, fmaf(a.z, wc.z, fmaf(a.y, wc.y, fmaf(a.x, wc.x, acc[r][2]))));
            sk[r][0]  = fmaf(xv.w, sa.w, fmaf(xv.z, sa.z, fmaf(xv.y, sa.y, fmaf(xv.x, sa.x, sk[r][0]))));
            sk[r][1]  = fmaf(xv.w, sb.w, fmaf(xv.z, sb.z, fmaf(xv.y, sb.y, fmaf(xv.x, sb.x, sk[r][1]))));
            sk[r][2]  = fmaf(xv.w, scv.w, fmaf(xv.z, scv.z, fmaf(xv.y, scv.y, fmaf(xv.x, scv.x, sk[r][2]))));
        }
    }
    float b00 = b0[l], b01 = b0[l + 32], b02 = b0[l + 64];
    float g0 = ln_g[l], g1 = ln_g[l + 32], g2 = ln_g[l + 64];
    float e0 = ln_b[l], e1 = ln_b[l + 32], e2 = ln_b[l + 64];
    float q0 = bs[l],   q1 = bs[l + 32],   q2 = bs[l + 64];
    #pragma unroll
    for (int r = 0; r < 4; ++r) {
        int node = base + r0 + r;
        if (node >= n) break;
        float a0v = acc[r][0] + b00, a1v = acc[r][1] + b01, a2v = acc[r][2] + b02;
        float s1 = a0v + a1v + a2v;
        #pragma unroll
        for (int off = 1; off < 32; off <<= 1) s1 += __shfl_xor(s1, off);
        float mu = s1 * (1.0f / 96.0f);
        float d0 = a0v - mu, d1 = a1v - mu, d2 = a2v - mu;
        float sq = d0 * d0 + d1 * d1 + d2 * d2;
        #pragma unroll
        for (int off = 1; off < 32; off <<= 1) sq += __shfl_xor(sq, off);
        float rinv = rsqrtf(sq * (1.0f / 96.0f) + LN_EPS);
        float di = dinv[node];
        float v0 = (fmaxf(d0 * rinv * g0 + e0, 0.0f) + sk[r][0] + q0) * di;
        float v1 = (fmaxf(d1 * rinv * g1 + e1, 0.0f) + sk[r][1] + q1) * di;
        float v2 = (fmaxf(d2 * rinv * g2 + e2, 0.0f) + sk[r][2] + q2) * di;
        unsigned short* o = hb + (size_t)node * 96;
        o[l]      = (unsigned short)f2bfbits(v0);
        o[l + 32] = (unsigned short)f2bfbits(v1);
        o[l + 64] = (unsigned short)f2bfbits(v2);
    }
}

// ---------------- FUSED agg96 + gemm_out ----------------
// hb holds hs = h * dinv[src]; agg[d] = dinv[d] * (sum ew_p * hs[s_p] + hs[d]).
// 4 independent edge streams (no dinv gather in loop); cooperative phase-2 GEMM.
__global__ __launch_bounds__(1024, 8) void agg96_out_kernel(
        const unsigned short* __restrict__ hb, const float* __restrict__ dinv,
        const int* __restrict__ rowptr, const uint2* __restrict__ cv,
        const float4* __restrict__ w1i, const float* __restrict__ b1,
        float* __restrict__ out, int n) {
    __shared__ float4 w1s[2304];   // [24][96]
    __shared__ float4 hr[384];     // 16 waves x 24 float4 (96 floats each)
    int t = threadIdx.x;
    for (int i = t; i < 2304; i += 1024) w1s[i] = w1i[i];
    int w = t >> 6;
    int node = blockIdx.x * 16 + w;
    int lane = t & 63;
    int g = lane >> 4, l4 = lane & 15;
    if (node < n) {
        const uint4* h4 = (const uint4*)hb;   // 16B = 8 bf16; row = 12 x uint4
        int p0 = rowptr[node], pe = rowptr[node + 1];
        float a0=0,a1=0,a2=0,a3=0,a4=0,a5=0,a6=0,a7=0;
        float c0=0,c1=0,c2=0,c3=0,c4=0,c5=0,c6=0,c7=0;
        if (l4 < 12) {
            for (int p = p0 + g; p < pe; p += 16) {
                bool h2 = (p + 4) < pe, h3 = (p + 8) < pe, hh4 = (p + 12) < pe;
                uint2 e1 = cv[p];
                uint2 e2 = h2  ? cv[p + 4]  : e1;
                uint2 e3 = h3  ? cv[p + 8]  : e1;
                uint2 e4 = hh4 ? cv[p + 12] : e1;
                float w1 = __uint_as_float(e1.y);
                float w2 = h2  ? __uint_as_float(e2.y) : 0.0f;
                float w3 = h3  ? __uint_as_float(e3.y) : 0.0f;
                float w4 = hh4 ? __uint_as_float(e4.y) : 0.0f;
                uint4 r1 = h4[(size_t)e1.x * 12 + l4];
                uint4 r2 = h4[(size_t)e2.x * 12 + l4];
                uint4 r3 = h4[(size_t)e3.x * 12 + l4];
                uint4 r4 = h4[(size_t)e4.x * 12 + l4];
                a0 = fmaf(w1, bflo(r1.x), a0); a1 = fmaf(w1, bfhi(r1.x), a1);
                a2 = fmaf(w1, bflo(r1.y), a2); a3 = fmaf(w1, bfhi(r1.y), a3);
                a4 = fmaf(w1, bflo(r1.z), a4); a5 = fmaf(w1, bfhi(r1.z), a5);
                a6 = fmaf(w1, bflo(r1.w), a6); a7 = fmaf(w1, bfhi(r1.w), a7);
                c0 = fmaf(w2, bflo(r2.x), c0); c1 = fmaf(w2, bfhi(r2.x), c1);
                c2 = fmaf(w2, bflo(r2.y), c2); c3 = fmaf(w2, bfhi(r2.y), c3);
                c4 = fmaf(w2, bflo(r2.z), c4); c5 = fmaf(w2, bfhi(r2.z), c5);
                c6 = fmaf(w2, bflo(r2.w), c6); c7 = fmaf(w2, bfhi(r2.w), c7);
                a0 = fmaf(w3, bflo(r3.x), a0); a1 = fmaf(w3, bfhi(r3.x), a1);
                a2 = fmaf(w3, bflo(r3.y), a2); a3 = fmaf(w3, bfhi(r3.y), a3);
                a4 = fmaf(w3, bflo(r3.z), a4); a5 = fmaf(w3, bfhi(r3.z), a5);
                a6 = fmaf(w3, bflo(r3.w), a6); a7 = fmaf(w3, bfhi(r3.w), a7);
                c0 = fmaf(w4, bflo(r4.x), c0); c1 = fmaf(w4, bfhi(r4.x), c1);
                c2 = fmaf(w4, bflo(r4.y), c2); c3 = fmaf(w4, bfhi(r4.y), c3);
                c4 = fmaf(w4, bflo(r4.z), c4); c5 = fmaf(w4, bfhi(r4.z), c5);
                c6 = fmaf(w4, bflo(r4.w), c6); c7 = fmaf(w4, bfhi(r4.w), c7);
            }
            a0+=c0; a1+=c1; a2+=c2; a3+=c3; a4+=c4; a5+=c5; a6+=c6; a7+=c7;
        }
        #pragma unroll
        for (int off = 16; off <= 32; off <<= 1) {
            a0 += __shfl_xor(a0, off); a1 += __shfl_xor(a1, off);
            a2 += __shfl_xor(a2, off); a3 += __shfl_xor(a3, off);
            a4 += __shfl_xor(a4, off); a5 += __shfl_xor(a5, off);
            a6 += __shfl_xor(a6, off); a7 += __shfl_xor(a7, off);
        }
        if (g == 0 && l4 < 12) {
            float di = dinv[node];
            const uint4* h4b2 = (const uint4*)hb;
            uint4 sr = h4b2[(size_t)node * 12 + l4];
            a0 += bflo(sr.x); a1 += bfhi(sr.x);
            a2 += bflo(sr.y); a3 += bfhi(sr.y);
            a4 += bflo(sr.z); a5 += bfhi(sr.z);
            a6 += bflo(sr.w); a7 += bfhi(sr.w);
            hr[w * 24 + l4 * 2]     = make_float4(a0 * di, a1 * di, a2 * di, a3 * di);
            hr[w * 24 + l4 * 2 + 1] = make_float4(a4 * di, a5 * di, a6 * di, a7 * di);
        }
    }
    __syncthreads();
    // phase 2: cooperative GEMM over the 16 staged rows
    int g32 = t >> 5, l = t & 31;
    if (g32 < 24) {
        int rp = g32 / 3;          // 0..7 -> rows rp*2, rp*2+1
        int cb = g32 % 3;          // col block 0..2
        int colbase = cb * 32 + l;
        int r0 = rp * 2;
        float acc0 = 0.f, acc1 = 0.f;
        #pragma unroll 4
        for (int kq = 0; kq < 24; ++kq) {
            float4 wv = w1s[kq * 96 + colbase];
            float4 a0 = hr[r0 * 24 + kq];
            float4 a1 = hr[(r0 + 1) * 24 + kq];
            acc0 = fmaf(a0.w, wv.w, fmaf(a0.z, wv.z, fmaf(a0.y, wv.y, fmaf(a0.x, wv.x, acc0))));
            acc1 = fmaf(a1.w, wv.w, fmaf(a1.z, wv.z, fmaf(a1.y, wv.y, fmaf(a1.x, wv.x, acc1))));
        }
        float bb = b1[colbase];
        int n0 = blockIdx.x * 16 + r0;
        if (n0 < n)     out[(size_t)n0 * 96 + colbase]       = acc0 + bb;
        if (n0 + 1 < n) out[(size_t)(n0 + 1) * 96 + colbase] = acc1 + bb;
    }
}

extern "C" void kernel_launch(void* const* d_in, const int* in_sizes, int n_in,
                              void* d_out, int out_size, void* d_ws, size_t ws_size,
                              hipStream_t stream) {
    const float* x    = (const float*)d_in[0];
    const int*   ei   = (const int*)d_in[1];
    const float* ew   = (const float*)d_in[2];
    const float* W0   = (const float*)d_in[3];
    const float* b0   = (const float*)d_in[4];
    const float* ln_g = (const float*)d_in[5];
    const float* ln_b = (const float*)d_in[6];
    const float* Ws   = (const float*)d_in[7];
    const float* bs   = (const float*)d_in[8];
    const float* W1   = (const float*)d_in[9];
    const float* b1   = (const float*)d_in[10];
    float* out = (float*)d_out;

    const int E = in_sizes[2];          // 800000
    const int N = in_sizes[0] / 64;     // 50000
    const int* src = ei;
    const int* dst = ei + E;

    char* ws = (char*)d_ws;
    size_t off = 0;
    auto alloc = [&](size_t bytes) -> void* {
        void* p = ws + off;
        off = (off + bytes + 255) & ~(size_t)255;
        return p;
    };
    float* dinv   = (float*)alloc((size_t)N * 4);
    int*   cnt    = (int*)alloc((size_t)N * 4);
    int*   rowptr = (int*)alloc((size_t)(N + 1) * 4);
    int*   rank   = (int*)alloc((size_t)E * 4);
    int*   bsum   = (int*)alloc((size_t)256 * 4);
    int*   boff   = (int*)alloc((size_t)256 * 4);
    uint2* cv     = (uint2*)alloc((size_t)E * 8);                // packed (col, raw ew)
    unsigned* xb  = (unsigned*)alloc((size_t)N * 64 * 2);        // bf16 x
    unsigned short* hb = (unsigned short*)alloc((size_t)N * 96 * 2);   // bf16 hs = h*dinv
    float* bufA   = (float*)alloc((size_t)N * 64 * 4);           // aggX
    float4* w0i   = (float4*)alloc((size_t)1536 * 16);           // k-interleaved weights
    float4* wsi   = (float4*)alloc((size_t)1536 * 16);
    float4* w1i   = (float4*)alloc((size_t)2304 * 16);

    int gN = (N + 255) / 256;
    int gE = (E + 255) / 256;
    int nb = (N + 1023) / 1024;
    int gX = (N * 16 + 255) / 256;
    int gC = (N / 4 + 255) / 256;
    int gM = gX > gE ? gX : gE;
    int gP = 8 * 128;                   // 8 partitions x 128 blocks

    zero_kernel<<<gC, 256, 0, stream>>>(cnt, N);
    cvtcnt_kernel<<<2 * gM + 15, 256, 0, stream>>>(x, xb, N * 16, dst, cnt, rank, E,
                                                   W0, Ws, W1, w0i, wsi, w1i, gM);
    blocksum_kernel<<<nb, 256, 0, stream>>>(cnt, bsum, N);
    scan_bsum_kernel<<<1, 64, 0, stream>>>(bsum, boff, nb);
    rowptr_kernel<<<nb, 256, 0, stream>>>(cnt, boff, rowptr, N, E);
    scatter_part_kernel<<<gP, 256, 0, stream>>>(src, dst, ew, rank, rowptr, cv, E, N);
    degsum_kernel<<<gN, 256, 0, stream>>>(rowptr, cv, dinv, N);

    int gA = (N + 3) / 4;
    agg64_kernel<<<gA, 256, 0, stream>>>(xb, dinv, rowptr, cv, bufA, N);

    int gG = (N + 63) / 64;
    gemm_ln_kernel<<<gG, 512, 0, stream>>>(w0i, wsi, bufA, x, dinv, b0, ln_g, ln_b, bs, hb, N);

    int gF = (N + 15) / 16;
    agg96_out_kernel<<<gF, 1024, 0, stream>>>(hb, dinv, rowptr, cv, w1i, b1, out, N);
}